// Round 2
// baseline (287.958 us; speedup 1.0000x reference)
//
#include <hip/hip_runtime.h>
#include <math.h>

typedef float vfloat4 __attribute__((ext_vector_type(4)));

__device__ __forceinline__ void set_lane(vfloat4& v, int k, float val) {
    // compile-time-constant lane indices only (avoid scratch, rule: no
    // runtime-indexed ext_vector)
    switch (k) {
        case 0: v.x = val; break;
        case 1: v.y = val; break;
        case 2: v.z = val; break;
        case 3: v.w = val; break;
    }
}

// Single kernel writes the entire output exactly once:
//   zeros + diagonal 1.0f + closed-form exp(i*H) 2x2 block at (i,i),(i,j),
//   (j,i),(j,j). Grid-stride persistent blocks (2048 x 256 = full occupancy,
//   one nontemporal float4 store per iter) — same store pattern as the rocclr
//   fillBufferAligned path that measures 6.6-6.7 TB/s in this harness, but
//   with zero extra dispatches or graph-node dependencies.
// Layout derived on-device: stride = out_size/N floats per row; mult =
// stride/N is 1 (real) or 2 (interleaved complex).
__global__ __launch_bounds__(256) void fill_all_kernel(
    vfloat4* __restrict__ out4, int out_size,
    const float* __restrict__ bii,
    const float* __restrict__ bjj,
    const float* __restrict__ bij_real,
    const float* __restrict__ bij_img,
    const int* __restrict__ conn_i,
    const int* __restrict__ conn_j,
    const int* __restrict__ Np)
{
    const int n = Np[0];                  // wave-uniform scalar load
    const int stride = out_size / n;      // floats per row (N or 2N)
    const int mult = stride / n;          // 1 (real) or 2 (complex)
    const int ls = 31 - __clz(stride);    // stride is a power of two
    const int mask = stride - 1;
    const int i = conn_i[0];
    const int j = conn_j[0];

    const int n_f4 = out_size >> 2;
    const int tid = blockIdx.x * 256 + threadIdx.x;
    const int nth = gridDim.x * 256;

    #pragma unroll 4
    for (int q = tid; q < n_f4; q += nth) {
        const int f = q << 2;             // float offset of this float4
        const int row = f >> ls;
        const int o = f & mask;           // float offset within row

        vfloat4 v = {0.f, 0.f, 0.f, 0.f};

        // Diagonal 1.0 (rare: one float4 per 4096 in the complex case).
        const int k = row * mult - o;
        if ((unsigned)k < 4u) set_lane(v, k, 1.0f);

        // 2x2 block rows (rare: only waves covering rows i or j).
        if (row == i || row == j) {
            const float a  = bii[0];
            const float b  = bjj[0];
            const float cr = bij_real[0];
            const float ci = bij_img[0];

            const float t  = 0.5f * (a + b);
            const float dd = 0.5f * (a - b);
            const float r  = sqrtf(dd * dd + cr * cr + ci * ci);
            const float sinc = (r > 0.f) ? (sinf(r) / r) : 1.0f;
            const float cosr = cosf(r);
            const float pr = cosf(t);     // phase = exp(i t)
            const float pim = sinf(t);

            const float sd = sinc * dd;
            float eii_r = pr * cosr - pim * sd;
            float eii_i = pr * sd + pim * cosr;
            float ejj_r = pr * cosr + pim * sd;
            float ejj_i = -pr * sd + pim * cosr;
            const float scr = -sinc * ci;   // i*sinc*c
            const float sci =  sinc * cr;
            float eij_r = pr * scr - pim * sci;
            float eij_i = pr * sci + pim * scr;
            const float sjr =  sinc * ci;   // i*sinc*conj(c)
            const float sji =  sinc * cr;
            const float eji_r = pr * sjr - pim * sji;
            const float eji_i = pr * sji + pim * sjr;

            // Reference write order is (i,i),(j,j),(i,j),(j,i) — if i==j all
            // four collapse to one cell and the LAST write (eji) wins.
            if (i == j) {
                eii_r = eji_r; eii_i = eji_i;
                ejj_r = eji_r; ejj_i = eji_i;
                eij_r = eji_r; eij_i = eji_i;
            }

            // This row's values at column i (c0) and column j (c1).
            float c0r, c0i, c1r, c1i;
            if (row == i) { c0r = eii_r; c0i = eii_i; c1r = eij_r; c1i = eij_i; }
            else          { c0r = eji_r; c0i = eji_i; c1r = ejj_r; c1i = ejj_i; }

            if (mult == 2) {              // interleaved complex: (re,im) pairs
                const int k0 = 2 * i - o; // pair start is even; f4 is aligned
                if ((unsigned)k0 < 4u) { set_lane(v, k0, c0r); set_lane(v, k0 + 1, c0i); }
                const int k1 = 2 * j - o;
                if ((unsigned)k1 < 4u) { set_lane(v, k1, c1r); set_lane(v, k1 + 1, c1i); }
            } else {                      // real-only matrix
                const int k0 = i - o;
                if ((unsigned)k0 < 4u) set_lane(v, k0, c0r);
                const int k1 = j - o;
                if ((unsigned)k1 < 4u) set_lane(v, k1, c1r);
            }
        }

        __builtin_nontemporal_store(v, out4 + q);
    }
}

extern "C" void kernel_launch(void* const* d_in, const int* in_sizes, int n_in,
                              void* d_out, int out_size, void* d_ws, size_t ws_size,
                              hipStream_t stream) {
    const float* bii      = (const float*)d_in[0];
    const float* bjj      = (const float*)d_in[1];
    const float* bij_real = (const float*)d_in[2];
    const float* bij_img  = (const float*)d_in[3];
    const int*   conn_i   = (const int*)d_in[4];
    const int*   conn_j   = (const int*)d_in[5];
    const int*   Np       = (const int*)d_in[6];

    const int n_f4 = out_size >> 2;
    int blocks = (n_f4 + 255) / 256;
    if (blocks > 2048) blocks = 2048;   // persistent grid: 8 blocks/CU, full occupancy

    fill_all_kernel<<<dim3(blocks), dim3(256), 0, stream>>>(
        (vfloat4*)d_out, out_size, bii, bjj, bij_real, bij_img,
        conn_i, conn_j, Np);
}

// Round 3
// 267.093 us; speedup vs baseline: 1.0781x; 1.0781x over previous
//
#include <hip/hip_runtime.h>
#include <math.h>

typedef float vfloat4 __attribute__((ext_vector_type(4)));

__device__ __forceinline__ void set_lane(vfloat4& v, int k, float val) {
    // runtime k, but executed once per block in the uniform prologue only
    switch (k) {
        case 0: v.x = val; break;
        case 1: v.y = val; break;
        case 2: v.z = val; break;
        case 3: v.w = val; break;
    }
}

// One block per row. Every row has at most TWO special float4s (the block
// cells at rows i/j REPLACE those rows' diagonal 1.0, so normal rows have
// exactly one: the diagonal). All special-case logic — trig, last-wins for
// i==j, merging two pairs that land in the same float4 — is hoisted into a
// wave-uniform prologue that builds register quads w0/w1 and their row-local
// float4 indices s0/s1. The hot loop is branch-free: cmp+cndmask-select the
// quad, one PLAIN global_store_dwordx4 (not nontemporal — matching the
// rocclr fillBufferAligned path that measures 6.6 TB/s; our NT-store fills
// measured only 4.6-5.7 TB/s in R0/R2).
__global__ __launch_bounds__(256) void fill_rows_kernel(
    float* __restrict__ out, int out_size,
    const float* __restrict__ bii,
    const float* __restrict__ bjj,
    const float* __restrict__ bij_real,
    const float* __restrict__ bij_img,
    const int* __restrict__ conn_i,
    const int* __restrict__ conn_j,
    const int* __restrict__ Np)
{
    const int n = Np[0];                  // wave-uniform
    const int stride = out_size / n;      // floats per row (N or 2N)
    const int mult = stride / n;          // 1 (real) or 2 (complex interleaved)
    const int i = conn_i[0];
    const int j = conn_j[0];

    const int row = blockIdx.x;
    if (row >= n) return;
    const bool isI = (row == i);
    const bool isJ = (row == j);

    // ---- uniform prologue: build up to two special float4 quads ----
    int s0, s1 = -1;                      // row-local float4 indices
    vfloat4 w0 = {0.f, 0.f, 0.f, 0.f};
    vfloat4 w1 = {0.f, 0.f, 0.f, 0.f};
    {
        int c0, c1 = -1;                  // row-local float offsets (cell starts)
        float v0r, v0i = 0.f, v1r = 0.f, v1i = 0.f;

        if (!isI && !isJ) {
            c0 = mult * row; v0r = 1.0f;  // plain diagonal
        } else {
            // closed-form exp(i*H), H = [[a, c],[conj(c), b]]:
            // t=(a+b)/2, d=(a-b)/2, r=sqrt(d^2+|c|^2)
            // exp(iH) = e^{it} (cos(r) I + i sinc(r) (H - t I))
            const float a  = bii[0];
            const float b  = bjj[0];
            const float cr = bij_real[0];
            const float ci = bij_img[0];

            const float t  = 0.5f * (a + b);
            const float dd = 0.5f * (a - b);
            const float r  = sqrtf(dd * dd + cr * cr + ci * ci);
            const float sinc = (r > 0.f) ? (sinf(r) / r) : 1.0f;
            const float cosr = cosf(r);
            const float pr  = cosf(t);    // phase = exp(i t)
            const float pim = sinf(t);

            const float sd = sinc * dd;
            const float eii_r = pr * cosr - pim * sd;
            const float eii_i = pr * sd + pim * cosr;
            const float ejj_r = pr * cosr + pim * sd;
            const float ejj_i = -pr * sd + pim * cosr;
            const float scr = -sinc * ci;     // i*sinc*c
            const float sci =  sinc * cr;
            const float eij_r = pr * scr - pim * sci;
            const float eij_i = pr * sci + pim * scr;
            const float sjr =  sinc * ci;     // i*sinc*conj(c)
            const float sji =  sinc * cr;
            const float eji_r = pr * sjr - pim * sji;
            const float eji_i = pr * sji + pim * sjr;

            if (i == j) {
                // reference writes ii, jj, ij, ji in order — last (ji) wins
                c0 = mult * i; v0r = eji_r; v0i = eji_i;
            } else if (isI) {
                c0 = mult * i; v0r = eii_r; v0i = eii_i;   // (i,i)
                c1 = mult * j; v1r = eij_r; v1i = eij_i;   // (i,j)
            } else {
                c0 = mult * i; v0r = eji_r; v0i = eji_i;   // (j,i)
                c1 = mult * j; v1r = ejj_r; v1i = ejj_i;   // (j,j)
            }
        }

        s0 = c0 >> 2;
        const int p0 = c0 & 3;            // mult==2 -> c0 even -> p0 in {0,2}
        set_lane(w0, p0, v0r);
        if (mult == 2) set_lane(w0, p0 + 1, v0i);

        if (c1 >= 0) {
            const int sB = c1 >> 2;
            const int p1 = c1 & 3;
            if (sB == s0) {               // both cells in one float4 (|i-j| small)
                set_lane(w0, p1, v1r);
                if (mult == 2) set_lane(w0, p1 + 1, v1i);
            } else {
                s1 = sB;
                set_lane(w1, p1, v1r);
                if (mult == 2) set_lane(w1, p1 + 1, v1i);
            }
        }
    }

    // ---- branch-free hot loop: plain dwordx4 stores over this row ----
    vfloat4* __restrict__ rowp = (vfloat4*)(out + (size_t)row * stride);
    const int nf4 = stride >> 2;          // float4s per row (4096 at N=8192 cplx)
    const vfloat4 zero = {0.f, 0.f, 0.f, 0.f};

    #pragma unroll 4
    for (int q = threadIdx.x; q < nf4; q += 256) {
        vfloat4 v = zero;
        if (q == s0) v = w0;              // compiles to cmp + cndmask, no branch
        if (q == s1) v = w1;
        rowp[q] = v;                      // plain global_store_dwordx4
    }
}

extern "C" void kernel_launch(void* const* d_in, const int* in_sizes, int n_in,
                              void* d_out, int out_size, void* d_ws, size_t ws_size,
                              hipStream_t stream) {
    const float* bii      = (const float*)d_in[0];
    const float* bjj      = (const float*)d_in[1];
    const float* bij_real = (const float*)d_in[2];
    const float* bij_img  = (const float*)d_in[3];
    const int*   conn_i   = (const int*)d_in[4];
    const int*   conn_j   = (const int*)d_in[5];
    const int*   Np       = (const int*)d_in[6];

    // One block per row; N is only known on-device, but out_size/N rows is
    // bounded by 8192 for this problem family. Launch 8192 blocks; extra
    // blocks (if N were smaller) exit on the row >= n guard.
    // For the bench problem: N=8192, stride=16384 floats, 4096 f4/row,
    // 16 stores/thread.
    fill_rows_kernel<<<dim3(8192), dim3(256), 0, stream>>>(
        (float*)d_out, out_size, bii, bjj, bij_real, bij_img,
        conn_i, conn_j, Np);
}

// Round 4
// 262.413 us; speedup vs baseline: 1.0973x; 1.0178x over previous
//
#include <hip/hip_runtime.h>
#include <math.h>

// R1 structure (best measured: 261.9 µs total, ~101 µs controllable):
//   hipMemsetAsync bulk zero  — rocclr fillBufferAligned path, measured
//     in-situ at 6.6-6.7 TB/s (82-84% HBM peak). Three hand-rolled fill
//     structures (NT mega-grid, NT fused persistent, plain-store per-row)
//     all measured slower (4.6-5.7 TB/s) — do not re-attempt.
//   diag_patch_kernel — one thread per row writes the diagonal 1.0f
//     (skipping rows i,j), thread 0 writes the closed-form exp(i*H) block.
__global__ __launch_bounds__(256) void diag_patch_kernel(
    float* __restrict__ out, int out_size,
    const float* __restrict__ bii,
    const float* __restrict__ bjj,
    const float* __restrict__ bij_real,
    const float* __restrict__ bij_img,
    const int* __restrict__ conn_i,
    const int* __restrict__ conn_j,
    const int* __restrict__ Np)
{
    const int n = Np[0];                 // wave-uniform scalar load
    const int stride = out_size / n;     // floats per row (N or 2N)
    const int mult = stride / n;         // 1 (real) or 2 (complex interleaved)

    const int i = conn_i[0];
    const int j = conn_j[0];

    const int gid = blockIdx.x * blockDim.x + threadIdx.x;
    const int nth = gridDim.x * blockDim.x;

    // Diagonal ones. Rows i and j get their diagonal from the patch below
    // (single writer per address — no ordering/race concern).
    for (int r = gid; r < n; r += nth) {
        if (r != i && r != j) {
            out[(size_t)r * stride + (size_t)mult * r] = 1.0f;
        }
    }

    if (gid != 0) return;

    // Closed-form exp(i*H) for Hermitian 2x2 H = [[a, c], [conj(c), b]]:
    //   t = (a+b)/2, d = (a-b)/2, r = sqrt(d^2 + |c|^2)
    //   exp(iH) = e^{it} (cos(r) I + i sinc(r) (H - t I))
    const float a  = bii[0];
    const float b  = bjj[0];
    const float cr = bij_real[0];
    const float ci = bij_img[0];

    const float t = 0.5f * (a + b);
    const float d = 0.5f * (a - b);
    const float r = sqrtf(d * d + cr * cr + ci * ci);
    const float sinc = (r > 0.f) ? (sinf(r) / r) : 1.0f;
    const float cosr = cosf(r);
    const float pr = cosf(t);   // phase = exp(i t)
    const float pi = sinf(t);

    const float sd = sinc * d;
    const float eii_r = pr * cosr - pi * sd;
    const float eii_i = pr * sd + pi * cosr;
    const float ejj_r = pr * cosr + pi * sd;
    const float ejj_i = -pr * sd + pi * cosr;
    const float sc_r = -sinc * ci;          // i*sinc*c     = (-sinc*ci, sinc*cr)
    const float sc_i = sinc * cr;
    const float eij_r = pr * sc_r - pi * sc_i;
    const float eij_i = pr * sc_i + pi * sc_r;
    const float sj_r = sinc * ci;           // i*sinc*conj(c) = (sinc*ci, sinc*cr)
    const float sj_i = sinc * cr;
    const float eji_r = pr * sj_r - pi * sj_i;
    const float eji_i = pr * sj_i + pi * sj_r;

    // Write order ii, jj, ij, ji: matches last-wins semantics if i == j.
    if (mult == 2) {  // interleaved complex
        size_t idx;
        idx = (size_t)i * stride + 2 * (size_t)i; out[idx] = eii_r; out[idx + 1] = eii_i;
        idx = (size_t)j * stride + 2 * (size_t)j; out[idx] = ejj_r; out[idx + 1] = ejj_i;
        idx = (size_t)i * stride + 2 * (size_t)j; out[idx] = eij_r; out[idx + 1] = eij_i;
        idx = (size_t)j * stride + 2 * (size_t)i; out[idx] = eji_r; out[idx + 1] = eji_i;
    } else {          // real-only matrix
        out[(size_t)i * stride + i] = eii_r;
        out[(size_t)j * stride + j] = ejj_r;
        out[(size_t)i * stride + j] = eij_r;
        out[(size_t)j * stride + i] = eji_r;
    }
}

extern "C" void kernel_launch(void* const* d_in, const int* in_sizes, int n_in,
                              void* d_out, int out_size, void* d_ws, size_t ws_size,
                              hipStream_t stream) {
    const float* bii      = (const float*)d_in[0];
    const float* bjj      = (const float*)d_in[1];
    const float* bij_real = (const float*)d_in[2];
    const float* bij_img  = (const float*)d_in[3];
    const int*   conn_i   = (const int*)d_in[4];
    const int*   conn_j   = (const int*)d_in[5];
    const int*   Np       = (const int*)d_in[6];

    float* out = (float*)d_out;

    // Bulk zero: runtime memset path (graph-capturable as a memset node),
    // measured at 82-84% of HBM peak in this harness.
    hipMemsetAsync(d_out, 0, (size_t)out_size * sizeof(float), stream);

    // One small kernel: diagonal ones + 2x2 block patch.
    // 32 blocks x 256 threads = 8192 threads: exactly one per row at N=8192.
    diag_patch_kernel<<<dim3(32), dim3(256), 0, stream>>>(
        out, out_size, bii, bjj, bij_real, bij_img, conn_i, conn_j, Np);
}